// Round 1
// baseline (221.807 us; speedup 1.0000x reference)
//
#include <hip/hip_runtime.h>
#include <math.h>

// Problem constants (from reference): features [B,H,W,D,F] float32
#define BB 16
#define HH 128
#define WW 128
#define DD 8
#define FF 16

// Fused: rotate(40deg, NN, expand=False, fill=0) -> roll((5,-7),(H,W)) -> flip(W,D)
// out[b,h,w,d,f] = valid(i,j) ? feat[b, si(i,j), sj(i,j), 7-d, f] : 0
//   i = (h - 5) mod H ; j = (W-1-w + 7) mod W = (134 - w) mod W
//
// Rotation map computed per-thread in f64 (exact map; rint = half-to-even,
// matching np.round). cos/sin(40deg) as correctly-rounded double constants.

__global__ __launch_bounds__(256) void aug_kernel(const float4* __restrict__ in,
                                                  float4* __restrict__ out,
                                                  int n_vec4) {
    int tid = blockIdx.x * blockDim.x + threadIdx.x;  // one float4 of output
    if (tid >= n_vec4) return;

    // decompose: tid = ((((b*H + h)*W + w)*D + d)*4 + f4)
    int t  = tid;
    int f4 = t & 3;   t >>= 2;
    int d  = t & 7;   t >>= 3;
    int w  = t & 127; t >>= 7;
    int h  = t & 127; t >>= 7;
    int b  = t;       // 0..15

    // compose roll + W-flip into rotated-space coords
    int i = (h + 123) & 127;   // (h - 5) mod 128
    int j = (134 - w) & 127;

    // inverse-rotation NN map (f64, exact)
    const double c = 0.76604444311897803;  // cos(40 deg)
    const double s = 0.64278760968653933;  // sin(40 deg)
    const double cy = 63.5, cx = 63.5;
    double di = (double)i - cy;
    double dj = (double)j - cx;
    double src_i = c * di + s * dj + cy;
    double src_j = -s * di + c * dj + cx;
    int si = (int)rint(src_i);
    int sj = (int)rint(src_j);
    bool valid = (si >= 0) & (si < HH) & (sj >= 0) & (sj < WW);

    float4 v = make_float4(0.f, 0.f, 0.f, 0.f);
    if (valid) {
        int dd = 7 - d;  // D-flip
        // float4-granular source index: F=16 floats = 4 float4 per (b,h,w,d)
        long long src = ((((long long)b * HH + si) * WW + sj) * DD + dd) * 4 + f4;
        v = in[src];
    }
    out[tid] = v;
}

extern "C" void kernel_launch(void* const* d_in, const int* in_sizes, int n_in,
                              void* d_out, int out_size, void* d_ws, size_t ws_size,
                              hipStream_t stream) {
    const float4* in = (const float4*)d_in[0];
    float4* out = (float4*)d_out;
    int n_vec4 = out_size / 4;  // 33554432 / 4 = 8388608
    int block = 256;
    int grid = (n_vec4 + block - 1) / block;  // 32768
    aug_kernel<<<grid, block, 0, stream>>>(in, out, n_vec4);
}